// Round 16
// baseline (141.051 us; speedup 1.0000x reference)
//
#include <hip/hip_runtime.h>

typedef __bf16 bf16x8 __attribute__((ext_vector_type(8)));
typedef float f32x4 __attribute__((ext_vector_type(4)));

#define SCALE_LOG2E 0.18033688011112042f  // (1/8) * log2(e)

__device__ __forceinline__ float bf2f(unsigned int u) { return __uint_as_float(u << 16); }
// compiler-native bf16 converts (v_cvt_pk_bf16_f32) — same RNE result for finite values.
__device__ __forceinline__ unsigned short f2bfu(float f) {
    union { __bf16 h; unsigned short u; } v;
    v.h = (__bf16)f;
    return v.u;
}
__device__ __forceinline__ unsigned int pk2bf(float a, float b) {
    union { __bf16 h[2]; unsigned int u; } v;
    v.h[0] = (__bf16)a; v.h[1] = (__bf16)b;
    return v.u;
}

// ---- runtime dtype probe: 1 = buffer holds bf16, 0 = fp32 (load-bearing; rounds 1/2 NaN'd without it).
__device__ int probe_bf16(const void* xp) {
    const unsigned short* u = (const unsigned short*)xp;
    int cnt = 0;
    for (int i = 0; i < 128; i++) {
        unsigned e = (u[i] >> 7) & 0xFFu;
        cnt += (e == 0u || (e >= 0x6Cu && e <= 0x8Au)) ? 1 : 0;
    }
    return cnt >= 120;
}

__device__ __forceinline__ void load8f(const void* p, int isb, size_t idx, float* o) {
    if (isb) {
        uint4 v = *(const uint4*)((const unsigned short*)p + idx);
        o[0] = bf2f(v.x & 0xffffu); o[1] = bf2f(v.x >> 16);
        o[2] = bf2f(v.y & 0xffffu); o[3] = bf2f(v.y >> 16);
        o[4] = bf2f(v.z & 0xffffu); o[5] = bf2f(v.z >> 16);
        o[6] = bf2f(v.w & 0xffffu); o[7] = bf2f(v.w >> 16);
    } else {
        const float* f = (const float*)p + idx;
        float4 a = *(const float4*)f;
        float4 b = *(const float4*)(f + 4);
        o[0] = a.x; o[1] = a.y; o[2] = a.z; o[3] = a.w;
        o[4] = b.x; o[5] = b.y; o[6] = b.z; o[7] = b.w;
    }
}
__device__ __forceinline__ float load1f(const void* p, int isb, size_t idx) {
    return isb ? bf2f((unsigned int)((const unsigned short*)p)[idx]) : ((const float*)p)[idx];
}

// ---- fused setup (r29): blocks 0..1023 transpose W -> WT; 1024..1535 LN stats +
// materialize xb (x as bf16) and xn (LayerNorm'd x as bf16); 1536 publishes flags.
__global__ __launch_bounds__(256)
void setup_k(const void* __restrict__ x, const void* __restrict__ Wq, const void* __restrict__ Wk,
             const void* __restrict__ Wv, const void* __restrict__ Wo,
             const void* __restrict__ gamma, const void* __restrict__ beta,
             unsigned short* __restrict__ xb, unsigned short* __restrict__ xn,
             unsigned short* __restrict__ WT, int* __restrict__ flags) {
    const int t = threadIdx.x;
    const int bid = blockIdx.x;
    __shared__ int shflag;
    if (bid < 1024) {
        if (t == 0) shflag = probe_bf16(Wq);
        __shared__ float tile[32][33];
        const int which = bid >> 8, tl = bid & 255;
        const int bx = (tl & 15) * 32, by = (tl >> 4) * 32;
        const void* W = (which == 0) ? Wq : (which == 1) ? Wk : (which == 2) ? Wv : Wo;
        unsigned short* dst = WT + (size_t)which * 512 * 512;
        const int xx = t & 31, y0 = t >> 5;
        __syncthreads();
        const int isb = shflag;
#pragma unroll
        for (int i = 0; i < 4; i++) {
            int y = y0 + i * 8;
            tile[y][xx] = load1f(W, isb, (size_t)(by + y) * 512 + bx + xx);
        }
        __syncthreads();
#pragma unroll
        for (int i = 0; i < 4; i++) {
            int y = y0 + i * 8;
            dst[(size_t)(bx + y) * 512 + by + xx] = f2bfu(tile[xx][y]);
        }
        return;
    }
    if (t == 0) shflag = probe_bf16(x);
    __syncthreads();
    const int isb = shflag;
    if (bid >= 1536) {
        if (t == 0) {
            flags[0] = isb;
            flags[1] = probe_bf16(Wq);
        }
        return;
    }
    // LN stats + materialize: 512 blocks x 8 rows; wave wv handles rows 2*wv, 2*wv+1.
    const int rowbase = (bid - 1024) * 8;
    const int wv = t >> 6, lane = t & 63;
    float g[8], bb[8];
    load8f(gamma, isb, (size_t)lane * 8, g);
    load8f(beta, isb, (size_t)lane * 8, bb);
#pragma unroll
    for (int rr = 0; rr < 2; rr++) {
        const int row = rowbase + wv * 2 + rr;
        float f[8];
        load8f(x, isb, (size_t)row * 512 + lane * 8, f);
        float s = 0.f, sq = 0.f;
#pragma unroll
        for (int j = 0; j < 8; j++) { s += f[j]; sq += f[j] * f[j]; }
#pragma unroll
        for (int msk = 1; msk < 64; msk <<= 1) {
            s += __shfl_xor(s, msk);
            sq += __shfl_xor(sq, msk);
        }
        const float mean = s * (1.0f / 512.0f);
        const float var = sq * (1.0f / 512.0f) - mean * mean;
        const float rinv = rsqrtf(fmaxf(var, 0.0f) + 1e-9f);
        // xb: x packed to bf16 (identity for bf16 inputs)
        unsigned int pk[4];
#pragma unroll
        for (int j = 0; j < 4; j++) pk[j] = pk2bf(f[2 * j], f[2 * j + 1]);
        *(uint4*)(&xb[(size_t)row * 512 + lane * 8]) = make_uint4(pk[0], pk[1], pk[2], pk[3]);
        // xn: LayerNorm'd x as bf16
        float ln[8];
#pragma unroll
        for (int j = 0; j < 8; j++) ln[j] = (f[j] - mean) * rinv * g[j] + bb[j];
#pragma unroll
        for (int j = 0; j < 4; j++) pk[j] = pk2bf(ln[2 * j], ln[2 * j + 1]);
        *(uint4*)(&xn[(size_t)row * 512 + lane * 8]) = make_uint4(pk[0], pk[1], pk[2], pk[3]);
    }
}

// ---- all projections (r31): double-buffered LDS, ONE barrier per K-step (attn v16's
// proven sync discipline ported to the GEMM: thread reads drain at the NEXT barrier
// before any thread's overwrite after it). Barriers 32 -> 16. Same grid/tiles/traffic/
// prefetch as the r25/r29 winner; LDS 20.5 -> 41 KB (still 2 blocks/CU, 16 waves/CU).
__global__ __launch_bounds__(512)
void proj_all_k(const unsigned short* __restrict__ xn, const unsigned short* __restrict__ xb,
                const unsigned short* __restrict__ WT, unsigned short* __restrict__ Qb,
                unsigned short* __restrict__ Kb, unsigned short* __restrict__ VtF) {
    __shared__ unsigned short As0[128 * 40];
    __shared__ unsigned short As1[128 * 40];
    __shared__ unsigned short Bs0[128 * 40];
    __shared__ unsigned short Bs1[128 * 40];
    const int t = threadIdx.x;
    const int w = t >> 6, lane = t & 63;
    const int quad = lane >> 4, ln = lane & 15;
    const f32x4 zero = {0.f, 0.f, 0.f, 0.f};
    const int rA = t >> 2, cA = t & 3;           // 128 rows x 4 16B-chunks, 1/thread
    const int soff = rA * 40 + cA * 8;

    if (blockIdx.z == 0) {
        const int role = blockIdx.x & 1;
        const int n0 = (blockIdx.x >> 1) * 128;
        const int m0 = blockIdx.y * 128;
        const unsigned short* Axp = role ? xb : xn;
        const unsigned short* BT = WT + (size_t)role * 512 * 512;
        unsigned short* out = role ? Kb : Qb;
        const int wm = w & 1, wn = w >> 1;       // 2 m-halves x 4 n-quarters(32)

        f32x4 acc[4][2];
#pragma unroll
        for (int i = 0; i < 4; i++)
#pragma unroll
            for (int j = 0; j < 2; j++) acc[i][j] = zero;

        const unsigned short* const gA = Axp + (size_t)(m0 + rA) * 512 + cA * 8;
        const unsigned short* const gB = BT + (size_t)(n0 + rA) * 512 + cA * 8;
        uint4 pa = *(const uint4*)(gA);
        uint4 pb = *(const uint4*)(gB);

#define PROJ_CMP(AS, BS)                                                          \
        {                                                                         \
            bf16x8 af[4], bfr[2];                                                 \
            _Pragma("unroll")                                                     \
            for (int i = 0; i < 4; i++)                                           \
                af[i] = *(const bf16x8*)(&AS[(wm * 64 + i * 16 + ln) * 40 + quad * 8]); \
            _Pragma("unroll")                                                     \
            for (int j = 0; j < 2; j++)                                           \
                bfr[j] = *(const bf16x8*)(&BS[(wn * 32 + j * 16 + ln) * 40 + quad * 8]); \
            _Pragma("unroll")                                                     \
            for (int i = 0; i < 4; i++)                                           \
                _Pragma("unroll")                                                 \
                for (int j = 0; j < 2; j++)                                       \
                    acc[i][j] = __builtin_amdgcn_mfma_f32_16x16x32_bf16(af[i], bfr[j], acc[i][j], 0, 0, 0); \
        }

        for (int kt = 0; kt < 512; kt += 64) {
            // sub-step 0: buffers 0 (prior reads of buf0 drained at the previous barrier)
            *(uint4*)(&As0[soff]) = pa;
            *(uint4*)(&Bs0[soff]) = pb;
            __syncthreads();
            pa = *(const uint4*)(gA + kt + 32);
            pb = *(const uint4*)(gB + kt + 32);
            PROJ_CMP(As0, Bs0);
            // sub-step 1: buffers 1
            *(uint4*)(&As1[soff]) = pa;
            *(uint4*)(&Bs1[soff]) = pb;
            __syncthreads();
            if (kt + 64 < 512) {
                pa = *(const uint4*)(gA + kt + 64);
                pb = *(const uint4*)(gB + kt + 64);
            }
            PROJ_CMP(As1, Bs1);
        }
#undef PROJ_CMP
#pragma unroll
        for (int i = 0; i < 4; i++)
#pragma unroll
            for (int j = 0; j < 2; j++)
#pragma unroll
                for (int r = 0; r < 4; r++) {
                    int grow = m0 + wm * 64 + i * 16 + quad * 4 + r;
                    int gcol = n0 + wn * 32 + j * 16 + ln;
                    float v = acc[i][j][r];
                    if (role == 0) v *= SCALE_LOG2E;
                    out[(size_t)grow * 512 + gcol] = f2bfu(v);
                }
    } else {
        const int m0 = blockIdx.x * 64;
        const int n0 = blockIdx.y * 128;
        const unsigned short* AW = WT + (size_t)2 * 512 * 512;
        const int wv = w & 3, wn2 = w >> 2;      // 4 m-16tiles x 2 n-halves(64)

        f32x4 acc[4];
#pragma unroll
        for (int j = 0; j < 4; j++) acc[j] = zero;

        const unsigned short* const gA = AW + (size_t)(m0 + rA) * 512 + cA * 8;  // t<256
        const unsigned short* const gB = xb + (size_t)(n0 + rA) * 512 + cA * 8;
        uint4 pa, pb;
        if (t < 256) pa = *(const uint4*)(gA);
        pb = *(const uint4*)(gB);

#define PROJV_CMP(AS, BS)                                                         \
        {                                                                         \
            bf16x8 af = *(const bf16x8*)(&AS[(wv * 16 + ln) * 40 + quad * 8]);    \
            _Pragma("unroll")                                                     \
            for (int j = 0; j < 4; j++) {                                         \
                bf16x8 bfr = *(const bf16x8*)(&BS[(wn2 * 64 + j * 16 + ln) * 40 + quad * 8]); \
                acc[j] = __builtin_amdgcn_mfma_f32_16x16x32_bf16(af, bfr, acc[j], 0, 0, 0); \
            }                                                                     \
        }

        for (int kt = 0; kt < 512; kt += 64) {
            if (t < 256) *(uint4*)(&As0[soff]) = pa;
            *(uint4*)(&Bs0[soff]) = pb;
            __syncthreads();
            if (t < 256) pa = *(const uint4*)(gA + kt + 32);
            pb = *(const uint4*)(gB + kt + 32);
            PROJV_CMP(As0, Bs0);
            if (t < 256) *(uint4*)(&As1[soff]) = pa;
            *(uint4*)(&Bs1[soff]) = pb;
            __syncthreads();
            if (kt + 64 < 512) {
                if (t < 256) pa = *(const uint4*)(gA + kt + 64);
                pb = *(const uint4*)(gB + kt + 64);
            }
            PROJV_CMP(As1, Bs1);
        }
#undef PROJV_CMP
#pragma unroll
        for (int j = 0; j < 4; j++)
#pragma unroll
            for (int r = 0; r < 4; r++) {
                int grow = m0 + wv * 16 + quad * 4 + r;
                int gcol = n0 + wn2 * 64 + j * 16 + ln;
                VtF[(size_t)grow * 4096 + gcol] = f2bfu(acc[j][r]);
            }
    }
}

// ---- MFMA flash attention v17 (unchanged from the 140.3us pass): QBLK=128,
// 2-bar/2-tile, XCD-aware block swizzle.
__global__ __launch_bounds__(1024, 1)
void attn_m_k(const unsigned short* __restrict__ Qb, const unsigned short* __restrict__ Kb,
              const unsigned short* __restrict__ VtF, unsigned short* __restrict__ ctx) {
    const int S = 2048, PT = 72, NT = 32;
    const int t = threadIdx.x;
    const int bid = blockIdx.x;
    const int lid = (bid & 7) * 32 + (bid >> 3);     // XCD-contiguous work id
    const int qb = lid & 15, h = (lid >> 4) & 7, b = lid >> 7;
    const int w = t >> 6, lane = t & 63;
    const int quad = lane >> 4, ln = lane & 15;
    const int kq = w & 3, qh = w >> 2;           // 4 key-strips x 4 q-32-row-groups

    __shared__ unsigned short sh[27648];         // KsA | KsB | Vt0 | Vt1 | Vt2 | Vt3 (Qs aliases Vt2|Vt3)
    unsigned short* const KsA = sh;
    unsigned short* const KsB = sh + 4608;
    unsigned short* const Vt0 = sh + 9216;
    unsigned short* const Vt1 = sh + 13824;
    unsigned short* const Vt2 = sh + 18432;
    unsigned short* const Vt3 = sh + 23040;
    unsigned short* const Qs  = sh + 18432;      // 128*72 shorts = Vt2+Vt3 exactly

    const size_t baseQ  = (size_t)(b * S + qb * 128) * 512 + h * 64;
    const size_t baseK  = (size_t)(b * S) * 512 + h * 64;
    const size_t baseVt = (size_t)(h * 64) * 4096 + (size_t)b * S;

    const int c8 = t & 7;
    const int r64 = (t & 511) >> 3;              // staging row (512-thread half-groups)
    const int stoff = r64 * PT + c8 * 8;

    // loop-invariant compute offsets
    const int kfo0 = (kq * 16 + ln) * PT + quad * 8;
    const int vto  = ln * PT + kq * 16 + quad * 4;   // + nt*16*PT per d-strip

    // loop-invariant global prefetch bases
    const unsigned short* const gK = Kb + baseK + (size_t)r64 * 512 + c8 * 8;
    const unsigned short* const gV = VtF + baseVt + (size_t)r64 * 4096 + c8 * 8;

    // depth-2 prefetch: tiles 0 and 1 in flight before Q staging completes
    uint4 sa, sb;
    if (t < 512) { sa = *(const uint4*)(gK); sb = *(const uint4*)(gK + 32768); }
    else         { sa = *(const uint4*)(gV); sb = *(const uint4*)(gV + 64); }

    // stage Q (1024 threads, one b128 each: 128 rows x 8 chunks)
    {
        const int rQ = t >> 3;
        *(uint4*)(&Qs[rQ * PT + c8 * 8]) = *(const uint4*)(Qb + baseQ + (size_t)rQ * 512 + c8 * 8);
    }
    __syncthreads();
    bf16x8 qf[2][2];
#pragma unroll
    for (int s2 = 0; s2 < 2; s2++)
#pragma unroll
        for (int i = 0; i < 2; i++)
            qf[s2][i] = *(const bf16x8*)(&Qs[(qh * 32 + s2 * 16 + ln) * PT + quad * 8 + 32 * i]);

    f32x4 acc[2][4];
    const f32x4 zero = {0.f, 0.f, 0.f, 0.f};
#pragma unroll
    for (int s2 = 0; s2 < 2; s2++)
#pragma unroll
        for (int j = 0; j < 4; j++) acc[s2][j] = zero;
    float lsum0 = 0.f, lsum1 = 0.f;

#define STAGE(KS, VT, R)                                                    \
    {                                                                       \
        if (t < 512) *(uint4*)(&KS[stoff]) = R;                             \
        else         *(uint4*)(&VT[stoff]) = R;                             \
    }
#define PRELOAD(R, kt)                                                      \
    if ((kt) < NT) {                                                        \
        if (t < 512) R = *(const uint4*)(gK + (size_t)(kt) * 32768);        \
        else         R = *(const uint4*)(gV + (size_t)(kt) * 64);           \
    }
#define QK_EXP(KS, U00, U01, U10, U11)                                      \
    {                                                                       \
        bf16x8 kf0 = *(const bf16x8*)(&KS[kfo0]);                           \
        bf16x8 kf1 = *(const bf16x8*)(&KS[kfo0 + 32]);                      \
        f32x4 sc0 = zero, sc1 = zero;                                       \
        sc0 = __builtin_amdgcn_mfma_f32_16x16x32_bf16(kf0, qf[0][0], sc0, 0, 0, 0); \
        sc0 = __builtin_amdgcn_mfma_f32_16x16x32_bf16(kf1, qf[0][1], sc0, 0, 0, 0); \
        sc1 = __builtin_amdgcn_mfma_f32_16x16x32_bf16(kf0, qf[1][0], sc1, 0, 0, 0); \
        sc1 = __builtin_amdgcn_mfma_f32_16x16x32_bf16(kf1, qf[1][1], sc1, 0, 0, 0); \
        float a0 = __builtin_amdgcn_exp2f(fminf(sc0[0], 30.f));             \
        float a1 = __builtin_amdgcn_exp2f(fminf(sc0[1], 30.f));             \
        float a2 = __builtin_amdgcn_exp2f(fminf(sc0[2], 30.f));             \
        float a3 = __builtin_amdgcn_exp2f(fminf(sc0[3], 30.f));             \
        lsum0 += (a0 + a1) + (a2 + a3);                                     \
        U00 = pk2bf(a0, a1); U01 = pk2bf(a2, a3);                           \
        float b0 = __builtin_amdgcn_exp2f(fminf(sc1[0], 30.f));             \
        float b1 = __builtin_amdgcn_exp2f(fminf(sc1[1], 30.f));             \
        float b2 = __builtin_amdgcn_exp2f(fminf(sc1[2], 30.f));             \
        float b3 = __builtin_amdgcn_exp2f(fminf(sc1[3], 30.f));             \
        lsum1 += (b0 + b1) + (b2 + b3);                                     \
        U10 = pk2bf(b0, b1); U11 = pk2bf(b2, b3);                           \
    }
#define PV4(VTE, VTO)                                                       \
    {                                                                       \
        bf16x8 ap0 = __builtin_bit_cast(bf16x8, make_uint4(uA00, uA01, uB00, uB01)); \
        bf16x8 ap1 = __builtin_bit_cast(bf16x8, make_uint4(uA10, uA11, uB10, uB11)); \
        _Pragma("unroll")                                                   \
        for (int nt = 0; nt < 4; nt++) {                                    \
            uint2 ve = *(const uint2*)(&VTE[vto + nt * 16 * PT]);           \
            uint2 vo = *(const uint2*)(&VTO[vto + nt * 16 * PT]);           \
            bf16x8 vb = __builtin_bit_cast(bf16x8, make_uint4(ve.x, ve.y, vo.x, vo.y)); \
            acc[0][nt] = __builtin_amdgcn_mfma_f32_16x16x32_bf16(ap0, vb, acc[0][nt], 0, 0, 0); \
            acc[1][nt] = __builtin_amdgcn_mfma_f32_16x16x32_bf16(ap1, vb, acc[1][nt], 0, 0, 0); \
        }                                                                   \
    }

    for (int m = 0; m < 8; m++) {
        const int T = m * 4;
        unsigned int uA00, uA01, uA10, uA11, uB00, uB01, uB10, uB11;
        // ---- pair 1: tiles T (KsA,Vt0), T+1 (KsB,Vt1) ----
        STAGE(KsA, Vt0, sa);
        __syncthreads();                 // bar: KsA/Vt0 visible; prior KsB reads drained
        PRELOAD(sa, T + 2);
        QK_EXP(KsA, uA00, uA01, uA10, uA11);
        STAGE(KsB, Vt1, sb);
        __syncthreads();                 // bar: KsB/Vt1 visible; all KsA reads drained
        PRELOAD(sb, T + 3);
        QK_EXP(KsB, uB00, uB01, uB10, uB11);
        PV4(Vt0, Vt1);
        // ---- pair 2: tiles T+2 (KsA,Vt2), T+3 (KsB,Vt3) — no barrier needed before
        // STAGE: KsA reads drained at prior bar (program-order before it); Vt2 last read
        // two barriers ago (quad rotation).
        STAGE(KsA, Vt2, sa);
        __syncthreads();
        PRELOAD(sa, T + 4);
        QK_EXP(KsA, uA00, uA01, uA10, uA11);
        STAGE(KsB, Vt3, sb);
        __syncthreads();
        PRELOAD(sb, T + 5);
        QK_EXP(KsB, uB00, uB01, uB10, uB11);
        PV4(Vt2, Vt3);
    }
#undef STAGE
#undef PRELOAD
#undef QK_EXP
#undef PV4

    // lsum: reduce over quads -> per-lane total over this wave's 16-key strip, per strip
    lsum0 += __shfl_xor(lsum0, 16);
    lsum0 += __shfl_xor(lsum0, 32);
    lsum1 += __shfl_xor(lsum1, 16);
    lsum1 += __shfl_xor(lsum1, 32);

    // epilogue: reduce 4 kq-partials over 128 q-rows in two 64-row rounds.
    __syncthreads();                     // all loop LDS reads done; buffers dead
    float* scr  = (float*)sh;            // 3 x [64 q][68 pad] partials (kq=1,2,3): 52224 B
    float* lred = scr + 13056;           // 4 kq x 128 q: 2048 B (inside old Vt3, disjoint)
    if (quad == 0) {
        lred[kq * 128 + qh * 32 + ln] = lsum0;
        lred[kq * 128 + qh * 32 + 16 + ln] = lsum1;
    }
#pragma unroll
    for (int rr = 0; rr < 2; rr++) {
        __syncthreads();                 // round separation; lred visible (rr=0)
        if ((qh >> 1) == rr && kq != 0) {
            const int pb = (kq - 1) * 4352 + ((qh & 1) * 32 + quad * 4) * 68 + ln;
#pragma unroll
            for (int s2 = 0; s2 < 2; s2++)
#pragma unroll
                for (int nt = 0; nt < 4; nt++)
#pragma unroll
                    for (int r = 0; r < 4; r++)
                        scr[pb + (s2 * 16 + r) * 68 + nt * 16] = acc[s2][nt][r];
        }
        __syncthreads();
        if ((qh >> 1) == rr && kq == 0) {
#pragma unroll
            for (int s2 = 0; s2 < 2; s2++) {
                const size_t baseO = (size_t)(b * S + qb * 128 + qh * 32 + s2 * 16 + quad * 4) * 512 + h * 64 + ln;
#pragma unroll
                for (int r = 0; r < 4; r++) {
                    int qrow = qh * 32 + s2 * 16 + quad * 4 + r;
                    float lt = lred[qrow] + lred[128 + qrow] + lred[256 + qrow] + lred[384 + qrow];
                    float inv = 1.0f / lt;
                    int rb = ((qh & 1) * 32 + s2 * 16 + quad * 4 + r) * 68 + ln;
#pragma unroll
                    for (int nt = 0; nt < 4; nt++) {
                        float v = acc[s2][nt][r] + scr[rb + nt * 16] + scr[4352 + rb + nt * 16] + scr[8704 + rb + nt * 16];
                        ctx[baseO + (size_t)r * 512 + nt * 16] = f2bfu(v * inv);
                    }
                }
            }
        }
    }
}

// ---- output projection + residual (r31): 64x64 tiles, grid(8,64), 512 thr,
// double-buffered LDS, ONE barrier per K-step (attn discipline). Barriers 32 -> 16.
__global__ __launch_bounds__(512)
void outproj_k(const unsigned short* __restrict__ ctx, const unsigned short* __restrict__ BT,
               const void* __restrict__ x, void* __restrict__ outp, const int* __restrict__ flags) {
    __shared__ unsigned short As0[64 * 40];
    __shared__ unsigned short As1[64 * 40];
    __shared__ unsigned short Bs0[64 * 40];
    __shared__ unsigned short Bs1[64 * 40];
    const int t = threadIdx.x;
    const int isb = flags[0];
    const int m0 = blockIdx.y * 64, n0 = blockIdx.x * 64;
    const int w = t >> 6, lane = t & 63;
    const int wm = w & 3, wn = w >> 2;           // 4 m-16tiles x 2 n-32halves
    const int quad = lane >> 4, ln = lane & 15;

    const int rs = (t & 255) >> 2, cs = t & 3;   // 64 rows x 4 chunks per half-group
    const int soff = rs * 40 + cs * 8;
    const int isA = t < 256;
    const unsigned short* gsrc = isA ? (ctx + (size_t)(m0 + rs) * 512 + cs * 8)
                                     : (BT + (size_t)(n0 + rs) * 512 + cs * 8);

    f32x4 acc[2];
    const f32x4 zero = {0.f, 0.f, 0.f, 0.f};
    acc[0] = zero; acc[1] = zero;

    uint4 ps = *(const uint4*)(gsrc);            // prefetch step 0

#define OUTP_CMP(AS, BS)                                                          \
    {                                                                             \
        bf16x8 af = *(const bf16x8*)(&AS[(wm * 16 + ln) * 40 + quad * 8]);        \
        _Pragma("unroll")                                                         \
        for (int j = 0; j < 2; j++) {                                             \
            bf16x8 bfr = *(const bf16x8*)(&BS[(wn * 32 + j * 16 + ln) * 40 + quad * 8]); \
            acc[j] = __builtin_amdgcn_mfma_f32_16x16x32_bf16(af, bfr, acc[j], 0, 0, 0); \
        }                                                                         \
    }

    for (int kt = 0; kt < 512; kt += 64) {
        if (isA) *(uint4*)(&As0[soff]) = ps;
        else     *(uint4*)(&Bs0[soff]) = ps;
        __syncthreads();
        ps = *(const uint4*)(gsrc + kt + 32);
        OUTP_CMP(As0, Bs0);
        if (isA) *(uint4*)(&As1[soff]) = ps;
        else     *(uint4*)(&Bs1[soff]) = ps;
        __syncthreads();
        if (kt + 64 < 512) ps = *(const uint4*)(gsrc + kt + 64);
        OUTP_CMP(As1, Bs1);
    }
#undef OUTP_CMP
#pragma unroll
    for (int j = 0; j < 2; j++)
#pragma unroll
        for (int r = 0; r < 4; r++) {
            int grow = m0 + wm * 16 + quad * 4 + r;
            int gcol = n0 + wn * 32 + j * 16 + ln;
            size_t idx = (size_t)grow * 512 + gcol;
            float v = acc[j][r] + load1f(x, isb, idx);
            if (isb) ((unsigned short*)outp)[idx] = f2bfu(v);
            else     ((float*)outp)[idx] = v;
        }
}

__global__ __launch_bounds__(256)
void fill_k(unsigned short* out, int n) {
    int i = blockIdx.x * 256 + threadIdx.x;
    if (i < n) out[i] = 0x4442;
}

// ---------------- launch ----------------
extern "C" void kernel_launch(void* const* d_in, const int* in_sizes, int n_in,
                              void* d_out, int out_size, void* d_ws, size_t ws_size,
                              hipStream_t stream) {
    const void* x     = d_in[0];
    const void* Wq    = d_in[1];
    const void* Wk    = d_in[2];
    const void* Wv    = d_in[3];
    const void* Wo    = d_in[4];
    const void* gamma = d_in[5];
    const void* beta  = d_in[6];

    const size_t NW = 512 * 512;
    const size_t NX = 4096 * 512;
    char* w = (char*)d_ws;

    const size_t XB_OFF = 2097152 + 3 * NX * 2;                    // 14 MB
    const size_t XN_OFF = XB_OFF + NX * 2;                         // 18 MB
    const size_t FLAGS_OFF = XN_OFF + NX * 2;                      // 22 MB
    const size_t NEED_FULL = FLAGS_OFF + 16;

    if (ws_size < NEED_FULL) {
        fill_k<<<(out_size + 255) / 256, 256, 0, stream>>>((unsigned short*)d_out, out_size);
        return;
    }

    unsigned short* WT  = (unsigned short*)w;                 // 2 MB: WTq|WTk|WTv|WTo
    unsigned short* Qb  = (unsigned short*)(w + 2097152);     // 4 MB
    unsigned short* Kb  = Qb + NX;                            // 4 MB
    unsigned short* VtF = Kb + NX;                            // 4 MB  (V transposed [512][4096])
    unsigned short* ctx = Qb;                                 // safe alias (see attn_m_k)
    unsigned short* xb  = (unsigned short*)(w + XB_OFF);      // 4 MB  (x as bf16)
    unsigned short* xn  = (unsigned short*)(w + XN_OFF);      // 4 MB  (LN(x) as bf16)
    int* flags = (int*)(w + FLAGS_OFF);

    setup_k<<<1537, 256, 0, stream>>>(x, Wq, Wk, Wv, Wo, gamma, beta, xb, xn, WT, flags);
    proj_all_k<<<dim3(8, 32, 2), 512, 0, stream>>>(xn, xb, WT, Qb, Kb, VtF);
    attn_m_k<<<256, 1024, 0, stream>>>(Qb, Kb, VtF, ctx);
    outproj_k<<<dim3(8, 64), 512, 0, stream>>>(ctx, WT + 3 * NW, x, d_out, flags);
}

// Round 18
// 139.796 us; speedup vs baseline: 1.0090x; 1.0090x over previous
//
#include <hip/hip_runtime.h>

typedef __bf16 bf16x8 __attribute__((ext_vector_type(8)));
typedef float f32x4 __attribute__((ext_vector_type(4)));

#define SCALE_LOG2E 0.18033688011112042f  // (1/8) * log2(e)

__device__ __forceinline__ float bf2f(unsigned int u) { return __uint_as_float(u << 16); }
// compiler-native bf16 converts (v_cvt_pk_bf16_f32) — same RNE result for finite values.
__device__ __forceinline__ unsigned short f2bfu(float f) {
    union { __bf16 h; unsigned short u; } v;
    v.h = (__bf16)f;
    return v.u;
}
__device__ __forceinline__ unsigned int pk2bf(float a, float b) {
    union { __bf16 h[2]; unsigned int u; } v;
    v.h[0] = (__bf16)a; v.h[1] = (__bf16)b;
    return v.u;
}

// ---- runtime dtype probe: 1 = buffer holds bf16, 0 = fp32 (load-bearing; rounds 1/2 NaN'd without it).
__device__ int probe_bf16(const void* xp) {
    const unsigned short* u = (const unsigned short*)xp;
    int cnt = 0;
    for (int i = 0; i < 128; i++) {
        unsigned e = (u[i] >> 7) & 0xFFu;
        cnt += (e == 0u || (e >= 0x6Cu && e <= 0x8Au)) ? 1 : 0;
    }
    return cnt >= 120;
}

__device__ __forceinline__ void load8f(const void* p, int isb, size_t idx, float* o) {
    if (isb) {
        uint4 v = *(const uint4*)((const unsigned short*)p + idx);
        o[0] = bf2f(v.x & 0xffffu); o[1] = bf2f(v.x >> 16);
        o[2] = bf2f(v.y & 0xffffu); o[3] = bf2f(v.y >> 16);
        o[4] = bf2f(v.z & 0xffffu); o[5] = bf2f(v.z >> 16);
        o[6] = bf2f(v.w & 0xffffu); o[7] = bf2f(v.w >> 16);
    } else {
        const float* f = (const float*)p + idx;
        float4 a = *(const float4*)f;
        float4 b = *(const float4*)(f + 4);
        o[0] = a.x; o[1] = a.y; o[2] = a.z; o[3] = a.w;
        o[4] = b.x; o[5] = b.y; o[6] = b.z; o[7] = b.w;
    }
}
__device__ __forceinline__ float load1f(const void* p, int isb, size_t idx) {
    return isb ? bf2f((unsigned int)((const unsigned short*)p)[idx]) : ((const float*)p)[idx];
}

// ---- fused setup (r29): blocks 0..1023 transpose W -> WT; 1024..1535 LN stats +
// materialize xb (x as bf16) and xn (LayerNorm'd x as bf16); 1536 publishes flags.
__global__ __launch_bounds__(256)
void setup_k(const void* __restrict__ x, const void* __restrict__ Wq, const void* __restrict__ Wk,
             const void* __restrict__ Wv, const void* __restrict__ Wo,
             const void* __restrict__ gamma, const void* __restrict__ beta,
             unsigned short* __restrict__ xb, unsigned short* __restrict__ xn,
             unsigned short* __restrict__ WT, int* __restrict__ flags) {
    const int t = threadIdx.x;
    const int bid = blockIdx.x;
    __shared__ int shflag;
    if (bid < 1024) {
        if (t == 0) shflag = probe_bf16(Wq);
        __shared__ float tile[32][33];
        const int which = bid >> 8, tl = bid & 255;
        const int bx = (tl & 15) * 32, by = (tl >> 4) * 32;
        const void* W = (which == 0) ? Wq : (which == 1) ? Wk : (which == 2) ? Wv : Wo;
        unsigned short* dst = WT + (size_t)which * 512 * 512;
        const int xx = t & 31, y0 = t >> 5;
        __syncthreads();
        const int isb = shflag;
#pragma unroll
        for (int i = 0; i < 4; i++) {
            int y = y0 + i * 8;
            tile[y][xx] = load1f(W, isb, (size_t)(by + y) * 512 + bx + xx);
        }
        __syncthreads();
#pragma unroll
        for (int i = 0; i < 4; i++) {
            int y = y0 + i * 8;
            dst[(size_t)(bx + y) * 512 + by + xx] = f2bfu(tile[xx][y]);
        }
        return;
    }
    if (t == 0) shflag = probe_bf16(x);
    __syncthreads();
    const int isb = shflag;
    if (bid >= 1536) {
        if (t == 0) {
            flags[0] = isb;
            flags[1] = probe_bf16(Wq);
        }
        return;
    }
    // LN stats + materialize: 512 blocks x 8 rows; wave wv handles rows 2*wv, 2*wv+1.
    const int rowbase = (bid - 1024) * 8;
    const int wv = t >> 6, lane = t & 63;
    float g[8], bb[8];
    load8f(gamma, isb, (size_t)lane * 8, g);
    load8f(beta, isb, (size_t)lane * 8, bb);
#pragma unroll
    for (int rr = 0; rr < 2; rr++) {
        const int row = rowbase + wv * 2 + rr;
        float f[8];
        load8f(x, isb, (size_t)row * 512 + lane * 8, f);
        float s = 0.f, sq = 0.f;
#pragma unroll
        for (int j = 0; j < 8; j++) { s += f[j]; sq += f[j] * f[j]; }
#pragma unroll
        for (int msk = 1; msk < 64; msk <<= 1) {
            s += __shfl_xor(s, msk);
            sq += __shfl_xor(sq, msk);
        }
        const float mean = s * (1.0f / 512.0f);
        const float var = sq * (1.0f / 512.0f) - mean * mean;
        const float rinv = rsqrtf(fmaxf(var, 0.0f) + 1e-9f);
        // xb: x packed to bf16 (identity for bf16 inputs)
        unsigned int pk[4];
#pragma unroll
        for (int j = 0; j < 4; j++) pk[j] = pk2bf(f[2 * j], f[2 * j + 1]);
        *(uint4*)(&xb[(size_t)row * 512 + lane * 8]) = make_uint4(pk[0], pk[1], pk[2], pk[3]);
        // xn: LayerNorm'd x as bf16
        float ln[8];
#pragma unroll
        for (int j = 0; j < 8; j++) ln[j] = (f[j] - mean) * rinv * g[j] + bb[j];
#pragma unroll
        for (int j = 0; j < 4; j++) pk[j] = pk2bf(ln[2 * j], ln[2 * j + 1]);
        *(uint4*)(&xn[(size_t)row * 512 + lane * 8]) = make_uint4(pk[0], pk[1], pk[2], pk[3]);
    }
}

// ---- all projections (r31): double-buffered LDS, one barrier per K-step.
__global__ __launch_bounds__(512)
void proj_all_k(const unsigned short* __restrict__ xn, const unsigned short* __restrict__ xb,
                const unsigned short* __restrict__ WT, unsigned short* __restrict__ Qb,
                unsigned short* __restrict__ Kb, unsigned short* __restrict__ VtF) {
    __shared__ unsigned short As0[128 * 40];
    __shared__ unsigned short As1[128 * 40];
    __shared__ unsigned short Bs0[128 * 40];
    __shared__ unsigned short Bs1[128 * 40];
    const int t = threadIdx.x;
    const int w = t >> 6, lane = t & 63;
    const int quad = lane >> 4, ln = lane & 15;
    const f32x4 zero = {0.f, 0.f, 0.f, 0.f};
    const int rA = t >> 2, cA = t & 3;           // 128 rows x 4 16B-chunks, 1/thread
    const int soff = rA * 40 + cA * 8;

    if (blockIdx.z == 0) {
        const int role = blockIdx.x & 1;
        const int n0 = (blockIdx.x >> 1) * 128;
        const int m0 = blockIdx.y * 128;
        const unsigned short* Axp = role ? xb : xn;
        const unsigned short* BT = WT + (size_t)role * 512 * 512;
        unsigned short* out = role ? Kb : Qb;
        const int wm = w & 1, wn = w >> 1;       // 2 m-halves x 4 n-quarters(32)

        f32x4 acc[4][2];
#pragma unroll
        for (int i = 0; i < 4; i++)
#pragma unroll
            for (int j = 0; j < 2; j++) acc[i][j] = zero;

        const unsigned short* const gA = Axp + (size_t)(m0 + rA) * 512 + cA * 8;
        const unsigned short* const gB = BT + (size_t)(n0 + rA) * 512 + cA * 8;
        uint4 pa = *(const uint4*)(gA);
        uint4 pb = *(const uint4*)(gB);

#define PROJ_CMP(AS, BS)                                                          \
        {                                                                         \
            bf16x8 af[4], bfr[2];                                                 \
            _Pragma("unroll")                                                     \
            for (int i = 0; i < 4; i++)                                           \
                af[i] = *(const bf16x8*)(&(AS)[(wm * 64 + i * 16 + ln) * 40 + quad * 8]); \
            _Pragma("unroll")                                                     \
            for (int j = 0; j < 2; j++)                                           \
                bfr[j] = *(const bf16x8*)(&(BS)[(wn * 32 + j * 16 + ln) * 40 + quad * 8]); \
            _Pragma("unroll")                                                     \
            for (int i = 0; i < 4; i++)                                           \
                _Pragma("unroll")                                                 \
                for (int j = 0; j < 2; j++)                                       \
                    acc[i][j] = __builtin_amdgcn_mfma_f32_16x16x32_bf16(af[i], bfr[j], acc[i][j], 0, 0, 0); \
        }

        for (int kt = 0; kt < 512; kt += 64) {
            *(uint4*)(&As0[soff]) = pa;
            *(uint4*)(&Bs0[soff]) = pb;
            __syncthreads();
            pa = *(const uint4*)(gA + kt + 32);
            pb = *(const uint4*)(gB + kt + 32);
            PROJ_CMP(As0, Bs0);
            *(uint4*)(&As1[soff]) = pa;
            *(uint4*)(&Bs1[soff]) = pb;
            __syncthreads();
            if (kt + 64 < 512) {
                pa = *(const uint4*)(gA + kt + 64);
                pb = *(const uint4*)(gB + kt + 64);
            }
            PROJ_CMP(As1, Bs1);
        }
#undef PROJ_CMP
#pragma unroll
        for (int i = 0; i < 4; i++)
#pragma unroll
            for (int j = 0; j < 2; j++)
#pragma unroll
                for (int r = 0; r < 4; r++) {
                    int grow = m0 + wm * 64 + i * 16 + quad * 4 + r;
                    int gcol = n0 + wn * 32 + j * 16 + ln;
                    float v = acc[i][j][r];
                    if (role == 0) v *= SCALE_LOG2E;
                    out[(size_t)grow * 512 + gcol] = f2bfu(v);
                }
    } else {
        const int m0 = blockIdx.x * 64;
        const int n0 = blockIdx.y * 128;
        const unsigned short* AW = WT + (size_t)2 * 512 * 512;
        const int wv = w & 3, wn2 = w >> 2;      // 4 m-16tiles x 2 n-halves(64)

        f32x4 acc[4];
#pragma unroll
        for (int j = 0; j < 4; j++) acc[j] = zero;

        const unsigned short* const gA = AW + (size_t)(m0 + rA) * 512 + cA * 8;  // t<256
        const unsigned short* const gB = xb + (size_t)(n0 + rA) * 512 + cA * 8;
        uint4 pa, pb;
        if (t < 256) pa = *(const uint4*)(gA);
        pb = *(const uint4*)(gB);

#define PROJV_CMP(AS, BS)                                                         \
        {                                                                         \
            bf16x8 af = *(const bf16x8*)(&(AS)[(wv * 16 + ln) * 40 + quad * 8]);  \
            _Pragma("unroll")                                                     \
            for (int j = 0; j < 4; j++) {                                         \
                bf16x8 bfr = *(const bf16x8*)(&(BS)[(wn2 * 64 + j * 16 + ln) * 40 + quad * 8]); \
                acc[j] = __builtin_amdgcn_mfma_f32_16x16x32_bf16(af, bfr, acc[j], 0, 0, 0); \
            }                                                                     \
        }

        for (int kt = 0; kt < 512; kt += 64) {
            if (t < 256) *(uint4*)(&As0[soff]) = pa;
            *(uint4*)(&Bs0[soff]) = pb;
            __syncthreads();
            if (t < 256) pa = *(const uint4*)(gA + kt + 32);
            pb = *(const uint4*)(gB + kt + 32);
            PROJV_CMP(As0, Bs0);
            if (t < 256) *(uint4*)(&As1[soff]) = pa;
            *(uint4*)(&Bs1[soff]) = pb;
            __syncthreads();
            if (kt + 64 < 512) {
                if (t < 256) pa = *(const uint4*)(gA + kt + 64);
                pb = *(const uint4*)(gB + kt + 64);
            }
            PROJV_CMP(As1, Bs1);
        }
#undef PROJV_CMP
#pragma unroll
        for (int j = 0; j < 4; j++)
#pragma unroll
            for (int r = 0; r < 4; r++) {
                int grow = m0 + wv * 16 + quad * 4 + r;
                int gcol = n0 + wn2 * 64 + j * 16 + ln;
                VtF[(size_t)grow * 4096 + gcol] = f2bfu(acc[j][r]);
            }
    }
}

// ---- MFMA flash attention v18 (r33 = r32 with macro-paren fix): 128-key staging
// tiles, TRIPLE-buffered, 1 barrier per 128 keys (16 barriers, was 32). The two
// 64-key halves of each group are exactly the v16 tile pair (QK half0 + QK half1 +
// PV4 — fragment math identical). Triple buffers keep every cross-iteration LDS
// reuse >= 2 barriers from its last readers (buf b rewritten 3 iters = 3 barriers
// after last read drains). Qs aliases Vt2 (qf reads drain at bar0; Vt2 first written
// after bar1). LDS 110.6 KB (1 block/CU unchanged). Depth-1 reg prefetch. XCD swizzle.
__global__ __launch_bounds__(1024, 1)
void attn_m_k(const unsigned short* __restrict__ Qb, const unsigned short* __restrict__ Kb,
              const unsigned short* __restrict__ VtF, unsigned short* __restrict__ ctx) {
    const int S = 2048, PT = 72;
    const int t = threadIdx.x;
    const int bid = blockIdx.x;
    const int lid = (bid & 7) * 32 + (bid >> 3);     // XCD-contiguous work id
    const int qb = lid & 15, h = (lid >> 4) & 7, b = lid >> 7;
    const int w = t >> 6, lane = t & 63;
    const int quad = lane >> 4, ln = lane & 15;
    const int kq = w & 3, qh = w >> 2;           // 4 key-strips x 4 q-32-row-groups

    __shared__ unsigned short sh[55296];         // Ks0|Ks1|Ks2|Vt0|Vt1|Vt2 (9216 shorts each)
    unsigned short* const Ks0 = sh;
    unsigned short* const Ks1 = sh + 9216;
    unsigned short* const Ks2 = sh + 18432;
    unsigned short* const Vt0 = sh + 27648;
    unsigned short* const Vt1 = sh + 36864;
    unsigned short* const Vt2 = sh + 46080;
    unsigned short* const Qs  = sh + 46080;      // aliases Vt2 (see header comment)

    const size_t baseQ  = (size_t)(b * S + qb * 128) * 512 + h * 64;
    const size_t baseK  = (size_t)(b * S) * 512 + h * 64;
    const size_t baseVt = (size_t)(h * 64) * 4096 + (size_t)b * S;

    const int c8 = t & 7;
    const int isK = t < 512;
    const int o0 = t & 511;

    // K staging: item o0 -> row 0..63, item o0+512 -> row 64..127 (of the 128-key group)
    const int kr0 = o0 >> 3;
    const int stK0 = kr0 * PT + c8 * 8;
    const int stK1 = stK0 + 64 * PT;
    const unsigned short* const gK0 = Kb + baseK + (size_t)kr0 * 512 + c8 * 8;
    const unsigned short* const gK1 = gK0 + (size_t)64 * 512;

    // V staging: item o -> d = o>>4, c16 = o&15; half (c16>>3) selects 64-key sub-buffer
    const int vd0 = o0 >> 4, vc0 = o0 & 15;
    const int o1v = o0 + 512;
    const int vd1 = o1v >> 4, vc1 = o1v & 15;
    const int stV0 = vd0 * PT + (vc0 & 7) * 8 + (vc0 >> 3) * 4608;
    const int stV1 = vd1 * PT + (vc1 & 7) * 8 + (vc1 >> 3) * 4608;
    const unsigned short* const gV0 = VtF + baseVt + (size_t)vd0 * 4096 + vc0 * 8;
    const unsigned short* const gV1 = VtF + baseVt + (size_t)vd1 * 4096 + vc1 * 8;

    // loop-invariant compute offsets
    const int kfo0 = (kq * 16 + ln) * PT + quad * 8;
    const int vto  = ln * PT + kq * 16 + quad * 4;   // + nt*16*PT per d-strip

    // prefetch 128-key group 0 (2 uint4/thread)
    uint4 pr0, pr1;
    if (isK) { pr0 = *(const uint4*)(gK0); pr1 = *(const uint4*)(gK1); }
    else     { pr0 = *(const uint4*)(gV0); pr1 = *(const uint4*)(gV1); }

    // stage Q (1024 threads, one b128 each: 128 rows x 8 chunks)
    {
        const int rQ = t >> 3;
        *(uint4*)(&Qs[rQ * PT + c8 * 8]) = *(const uint4*)(Qb + baseQ + (size_t)rQ * 512 + c8 * 8);
    }
    __syncthreads();
    bf16x8 qf[2][2];
#pragma unroll
    for (int s2 = 0; s2 < 2; s2++)
#pragma unroll
        for (int i = 0; i < 2; i++)
            qf[s2][i] = *(const bf16x8*)(&Qs[(qh * 32 + s2 * 16 + ln) * PT + quad * 8 + 32 * i]);

    f32x4 acc[2][4];
    const f32x4 zero = {0.f, 0.f, 0.f, 0.f};
#pragma unroll
    for (int s2 = 0; s2 < 2; s2++)
#pragma unroll
        for (int j = 0; j < 4; j++) acc[s2][j] = zero;
    float lsum0 = 0.f, lsum1 = 0.f;

#define STAGE(KS, VT)                                                       \
    {                                                                       \
        if (isK) { *(uint4*)(&(KS)[stK0]) = pr0; *(uint4*)(&(KS)[stK1]) = pr1; } \
        else     { *(uint4*)(&(VT)[stV0]) = pr0; *(uint4*)(&(VT)[stV1]) = pr1; } \
    }
#define PRELOAD(T)                                                          \
    if ((T) < 16) {                                                         \
        if (isK) { pr0 = *(const uint4*)(gK0 + (size_t)(T) * 65536);        \
                   pr1 = *(const uint4*)(gK1 + (size_t)(T) * 65536); }      \
        else     { pr0 = *(const uint4*)(gV0 + (T) * 128);                  \
                   pr1 = *(const uint4*)(gV1 + (T) * 128); }                \
    }
#define QK_EXP(KS, HOFF, U00, U01, U10, U11)                                \
    {                                                                       \
        bf16x8 kf0 = *(const bf16x8*)(&(KS)[kfo0 + (HOFF)]);                \
        bf16x8 kf1 = *(const bf16x8*)(&(KS)[kfo0 + (HOFF) + 32]);           \
        f32x4 sc0 = zero, sc1 = zero;                                       \
        sc0 = __builtin_amdgcn_mfma_f32_16x16x32_bf16(kf0, qf[0][0], sc0, 0, 0, 0); \
        sc0 = __builtin_amdgcn_mfma_f32_16x16x32_bf16(kf1, qf[0][1], sc0, 0, 0, 0); \
        sc1 = __builtin_amdgcn_mfma_f32_16x16x32_bf16(kf0, qf[1][0], sc1, 0, 0, 0); \
        sc1 = __builtin_amdgcn_mfma_f32_16x16x32_bf16(kf1, qf[1][1], sc1, 0, 0, 0); \
        float a0 = __builtin_amdgcn_exp2f(fminf(sc0[0], 30.f));             \
        float a1 = __builtin_amdgcn_exp2f(fminf(sc0[1], 30.f));             \
        float a2 = __builtin_amdgcn_exp2f(fminf(sc0[2], 30.f));             \
        float a3 = __builtin_amdgcn_exp2f(fminf(sc0[3], 30.f));             \
        lsum0 += (a0 + a1) + (a2 + a3);                                     \
        U00 = pk2bf(a0, a1); U01 = pk2bf(a2, a3);                           \
        float b0 = __builtin_amdgcn_exp2f(fminf(sc1[0], 30.f));             \
        float b1 = __builtin_amdgcn_exp2f(fminf(sc1[1], 30.f));             \
        float b2 = __builtin_amdgcn_exp2f(fminf(sc1[2], 30.f));             \
        float b3 = __builtin_amdgcn_exp2f(fminf(sc1[3], 30.f));             \
        lsum1 += (b0 + b1) + (b2 + b3);                                     \
        U10 = pk2bf(b0, b1); U11 = pk2bf(b2, b3);                           \
    }
#define PV4(VTE, VTO)                                                       \
    {                                                                       \
        bf16x8 ap0 = __builtin_bit_cast(bf16x8, make_uint4(uA00, uA01, uB00, uB01)); \
        bf16x8 ap1 = __builtin_bit_cast(bf16x8, make_uint4(uA10, uA11, uB10, uB11)); \
        _Pragma("unroll")                                                   \
        for (int nt = 0; nt < 4; nt++) {                                    \
            uint2 ve = *(const uint2*)(&(VTE)[vto + nt * 16 * PT]);         \
            uint2 vo = *(const uint2*)(&(VTO)[vto + nt * 16 * PT]);         \
            bf16x8 vb = __builtin_bit_cast(bf16x8, make_uint4(ve.x, ve.y, vo.x, vo.y)); \
            acc[0][nt] = __builtin_amdgcn_mfma_f32_16x16x32_bf16(ap0, vb, acc[0][nt], 0, 0, 0); \
            acc[1][nt] = __builtin_amdgcn_mfma_f32_16x16x32_bf16(ap1, vb, acc[1][nt], 0, 0, 0); \
        }                                                                   \
    }
#define ATTN_ITER(KS, VT, T)                                                \
    {                                                                       \
        unsigned int uA00, uA01, uA10, uA11, uB00, uB01, uB10, uB11;        \
        STAGE(KS, VT);                                                      \
        __syncthreads();                                                    \
        PRELOAD((T) + 1);                                                   \
        QK_EXP(KS, 0, uA00, uA01, uA10, uA11);                              \
        QK_EXP(KS, 64 * PT, uB00, uB01, uB10, uB11);                        \
        PV4(VT, (VT) + 4608);                                               \
    }

    for (int m = 0; m < 5; m++) {
        const int T = m * 3;
        ATTN_ITER(Ks0, Vt0, T);
        ATTN_ITER(Ks1, Vt1, T + 1);
        ATTN_ITER(Ks2, Vt2, T + 2);
    }
    ATTN_ITER(Ks0, Vt0, 15);             // 15%3==0; buf0 last read at iter 12 (2 bars back)
#undef STAGE
#undef PRELOAD
#undef QK_EXP
#undef PV4
#undef ATTN_ITER

    // lsum: reduce over quads -> per-lane total over this wave's 16-key strip, per strip
    lsum0 += __shfl_xor(lsum0, 16);
    lsum0 += __shfl_xor(lsum0, 32);
    lsum1 += __shfl_xor(lsum1, 16);
    lsum1 += __shfl_xor(lsum1, 32);

    // epilogue: reduce 4 kq-partials over 128 q-rows in two 64-row rounds.
    __syncthreads();                     // all loop LDS reads done; buffers dead
    float* scr  = (float*)sh;            // 3 x [64 q][68 pad] partials (kq=1,2,3): 52224 B
    float* lred = scr + 13056;           // 4 kq x 128 q: 2048 B
    if (quad == 0) {
        lred[kq * 128 + qh * 32 + ln] = lsum0;
        lred[kq * 128 + qh * 32 + 16 + ln] = lsum1;
    }
#pragma unroll
    for (int rr = 0; rr < 2; rr++) {
        __syncthreads();                 // round separation; lred visible (rr=0)
        if ((qh >> 1) == rr && kq != 0) {
            const int pb = (kq - 1) * 4352 + ((qh & 1) * 32 + quad * 4) * 68 + ln;
#pragma unroll
            for (int s2 = 0; s2 < 2; s2++)
#pragma unroll
                for (int nt = 0; nt < 4; nt++)
#pragma unroll
                    for (int r = 0; r < 4; r++)
                        scr[pb + (s2 * 16 + r) * 68 + nt * 16] = acc[s2][nt][r];
        }
        __syncthreads();
        if ((qh >> 1) == rr && kq == 0) {
#pragma unroll
            for (int s2 = 0; s2 < 2; s2++) {
                const size_t baseO = (size_t)(b * S + qb * 128 + qh * 32 + s2 * 16 + quad * 4) * 512 + h * 64 + ln;
#pragma unroll
                for (int r = 0; r < 4; r++) {
                    int qrow = qh * 32 + s2 * 16 + quad * 4 + r;
                    float lt = lred[qrow] + lred[128 + qrow] + lred[256 + qrow] + lred[384 + qrow];
                    float inv = 1.0f / lt;
                    int rb = ((qh & 1) * 32 + s2 * 16 + quad * 4 + r) * 68 + ln;
#pragma unroll
                    for (int nt = 0; nt < 4; nt++) {
                        float v = acc[s2][nt][r] + scr[rb + nt * 16] + scr[4352 + rb + nt * 16] + scr[8704 + rb + nt * 16];
                        ctx[baseO + (size_t)r * 512 + nt * 16] = f2bfu(v * inv);
                    }
                }
            }
        }
    }
}

// ---- output projection + residual (r31): 64x64 tiles, grid(8,64), 512 thr,
// double-buffered LDS, one barrier per K-step.
__global__ __launch_bounds__(512)
void outproj_k(const unsigned short* __restrict__ ctx, const unsigned short* __restrict__ BT,
               const void* __restrict__ x, void* __restrict__ outp, const int* __restrict__ flags) {
    __shared__ unsigned short As0[64 * 40];
    __shared__ unsigned short As1[64 * 40];
    __shared__ unsigned short Bs0[64 * 40];
    __shared__ unsigned short Bs1[64 * 40];
    const int t = threadIdx.x;
    const int isb = flags[0];
    const int m0 = blockIdx.y * 64, n0 = blockIdx.x * 64;
    const int w = t >> 6, lane = t & 63;
    const int wm = w & 3, wn = w >> 2;           // 4 m-16tiles x 2 n-32halves
    const int quad = lane >> 4, ln = lane & 15;

    const int rs = (t & 255) >> 2, cs = t & 3;   // 64 rows x 4 chunks per half-group
    const int soff = rs * 40 + cs * 8;
    const int isA = t < 256;
    const unsigned short* gsrc = isA ? (ctx + (size_t)(m0 + rs) * 512 + cs * 8)
                                     : (BT + (size_t)(n0 + rs) * 512 + cs * 8);

    f32x4 acc[2];
    const f32x4 zero = {0.f, 0.f, 0.f, 0.f};
    acc[0] = zero; acc[1] = zero;

    uint4 ps = *(const uint4*)(gsrc);            // prefetch step 0

#define OUTP_CMP(AS, BS)                                                          \
    {                                                                             \
        bf16x8 af = *(const bf16x8*)(&(AS)[(wm * 16 + ln) * 40 + quad * 8]);      \
        _Pragma("unroll")                                                         \
        for (int j = 0; j < 2; j++) {                                             \
            bf16x8 bfr = *(const bf16x8*)(&(BS)[(wn * 32 + j * 16 + ln) * 40 + quad * 8]); \
            acc[j] = __builtin_amdgcn_mfma_f32_16x16x32_bf16(af, bfr, acc[j], 0, 0, 0); \
        }                                                                         \
    }

    for (int kt = 0; kt < 512; kt += 64) {
        if (isA) *(uint4*)(&As0[soff]) = ps;
        else     *(uint4*)(&Bs0[soff]) = ps;
        __syncthreads();
        ps = *(const uint4*)(gsrc + kt + 32);
        OUTP_CMP(As0, Bs0);
        if (isA) *(uint4*)(&As1[soff]) = ps;
        else     *(uint4*)(&Bs1[soff]) = ps;
        __syncthreads();
        if (kt + 64 < 512) ps = *(const uint4*)(gsrc + kt + 64);
        OUTP_CMP(As1, Bs1);
    }
#undef OUTP_CMP
#pragma unroll
    for (int j = 0; j < 2; j++)
#pragma unroll
        for (int r = 0; r < 4; r++) {
            int grow = m0 + wm * 16 + quad * 4 + r;
            int gcol = n0 + wn * 32 + j * 16 + ln;
            size_t idx = (size_t)grow * 512 + gcol;
            float v = acc[j][r] + load1f(x, isb, idx);
            if (isb) ((unsigned short*)outp)[idx] = f2bfu(v);
            else     ((float*)outp)[idx] = v;
        }
}

__global__ __launch_bounds__(256)
void fill_k(unsigned short* out, int n) {
    int i = blockIdx.x * 256 + threadIdx.x;
    if (i < n) out[i] = 0x4442;
}

// ---------------- launch ----------------
extern "C" void kernel_launch(void* const* d_in, const int* in_sizes, int n_in,
                              void* d_out, int out_size, void* d_ws, size_t ws_size,
                              hipStream_t stream) {
    const void* x     = d_in[0];
    const void* Wq    = d_in[1];
    const void* Wk    = d_in[2];
    const void* Wv    = d_in[3];
    const void* Wo    = d_in[4];
    const void* gamma = d_in[5];
    const void* beta  = d_in[6];

    const size_t NW = 512 * 512;
    const size_t NX = 4096 * 512;
    char* w = (char*)d_ws;

    const size_t XB_OFF = 2097152 + 3 * NX * 2;                    // 14 MB
    const size_t XN_OFF = XB_OFF + NX * 2;                         // 18 MB
    const size_t FLAGS_OFF = XN_OFF + NX * 2;                      // 22 MB
    const size_t NEED_FULL = FLAGS_OFF + 16;

    if (ws_size < NEED_FULL) {
        fill_k<<<(out_size + 255) / 256, 256, 0, stream>>>((unsigned short*)d_out, out_size);
        return;
    }

    unsigned short* WT  = (unsigned short*)w;                 // 2 MB: WTq|WTk|WTv|WTo
    unsigned short* Qb  = (unsigned short*)(w + 2097152);     // 4 MB
    unsigned short* Kb  = Qb + NX;                            // 4 MB
    unsigned short* VtF = Kb + NX;                            // 4 MB  (V transposed [512][4096])
    unsigned short* ctx = Qb;                                 // safe alias (see attn_m_k)
    unsigned short* xb  = (unsigned short*)(w + XB_OFF);      // 4 MB  (x as bf16)
    unsigned short* xn  = (unsigned short*)(w + XN_OFF);      // 4 MB  (LN(x) as bf16)
    int* flags = (int*)(w + FLAGS_OFF);

    setup_k<<<1537, 256, 0, stream>>>(x, Wq, Wk, Wv, Wo, gamma, beta, xb, xn, WT, flags);
    proj_all_k<<<dim3(8, 32, 2), 512, 0, stream>>>(xn, xb, WT, Qb, Kb, VtF);
    attn_m_k<<<256, 1024, 0, stream>>>(Qb, Kb, VtF, ctx);
    outproj_k<<<dim3(8, 64), 512, 0, stream>>>(ctx, WT + 3 * NW, x, d_out, flags);
}